// Round 6
// baseline (144.639 us; speedup 1.0000x reference)
//
#include <hip/hip_runtime.h>
#include <hip/hip_bf16.h>

// QuantumKANLayer: S = [cos|sin features](32768x4096) @ W(4096x256), bf16 MFMA.
// R5: in-register A (Chebyshev chains per lane, no A-LDS, no A-barrier) +
//     B staged once per block per step into LDS (linear 32 KB memcpy of the
//     fragment-major pack; reg-staged with T14 issue-early/write-late) +
//     1024-thread blocks, 16 waves = 4M x 4N, wave = 32 rows x 64 cols.
//
// k-slot semantics (A and B agree): for k-slice i, slot h*8+e <->
// (h ? sin : cos)((e+1) * x[row][i]).

#define NSTEP 64         // 4096 k / 64 k-per-step; 4 i per step

typedef __attribute__((ext_vector_type(8)))  short short8;
typedef __attribute__((ext_vector_type(16))) float f32x16;

static __device__ __forceinline__ unsigned short f2bf(float f) {
    union { float f; unsigned u; } v; v.f = f;
    unsigned r = v.u + 0x7fff + ((v.u >> 16) & 1);   // RNE
    return (unsigned short)(r >> 16);
}

// ---- pack W^T fragment-major for 32x32x16 B-frags -------------------------
// flat idx = (i*8 + cg)*64 + l,  16B per idx.
// lane l: col j = cg*32 + (l&31), h = l>>5,
//         val[e] = (h ? coef_b : coef_a)[j][i][e]
__global__ __launch_bounds__(256) void pack_w_kernel(
        const float* __restrict__ ca, const float* __restrict__ cb,
        unsigned short* __restrict__ wt) {
    int idx = blockIdx.x * 256 + threadIdx.x;   // 131072
    int l  = idx & 63;
    int cg = (idx >> 6) & 7;
    int i  = idx >> 9;
    int j  = cg * 32 + (l & 31);
    const float* src = ((l >> 5) ? cb : ca) + ((size_t)j * 256 + i) * 8;
    float4 v0 = ((const float4*)src)[0];
    float4 v1 = ((const float4*)src)[1];
    alignas(16) unsigned short o[8];
    o[0] = f2bf(v0.x); o[1] = f2bf(v0.y); o[2] = f2bf(v0.z); o[3] = f2bf(v0.w);
    o[4] = f2bf(v1.x); o[5] = f2bf(v1.y); o[6] = f2bf(v1.z); o[7] = f2bf(v1.w);
    *(short8*)(wt + (size_t)idx * 8) = *(short8*)o;
}

// ---- fused feature-gen + GEMM --------------------------------------------
// grid 256, block 1024 = 16 waves (4M x 4N). Wave (wm,wn): rows
// bm0+wm*32..+31, cols wn*64..+63. B tile per step = 32 KB (4 i x 8 cg x 1KB),
// double-buffered in LDS, staged linearly (thread tid -> 16B granule tid).
template<bool PACKED>
__global__ __launch_bounds__(1024, 4) void kan_gemm(
        const float* __restrict__ x,
        const unsigned short* __restrict__ bwt,
        const float* __restrict__ ca, const float* __restrict__ cb,
        float* __restrict__ out) {
    __shared__ __align__(16) char Blds[2][32768];

    const int tid   = threadIdx.x;
    const int l     = tid & 63;
    const int w     = tid >> 6;       // 0..15
    const int lrow  = l & 31;
    const int lhalf = l >> 5;
    const int wm    = w & 3;          // 4 M-waves
    const int wn    = w >> 2;         // 4 N-waves
    const int bm0   = blockIdx.x * 128;
    const int cg0   = wn * 2;

    f32x16 acc[2];
#pragma unroll
    for (int n = 0; n < 2; ++n)
#pragma unroll
        for (int r = 0; r < 16; ++r) acc[n][r] = 0.0f;

    const float* xp = x + (size_t)(bm0 + wm * 32 + lrow) * 256;
    const float p2init = lhalf ? 0.0f : 1.0f;

    // staging registers (issue-early / write-late, T14)
    short8 sv0, sv1;

    auto stage_issue = [&](int s) {
        if (PACKED) {
            const short8* bp = (const short8*)(bwt + (size_t)s * 16384);
            sv0 = bp[tid];
            sv1 = bp[tid + 1024];
        } else {
#pragma unroll
            for (int p = 0; p < 2; ++p) {
                const int g  = p * 1024 + tid;
                const int lg = g & 63;
                const int cg = (g >> 6) & 7;
                const int t  = (g >> 9) & 3;
                const int j  = cg * 32 + (lg & 31);
                const int i  = s * 4 + t;
                const float* src = ((lg >> 5) ? cb : ca)
                                 + ((size_t)j * 256 + i) * 8;
                float4 v0 = ((const float4*)src)[0];
                float4 v1 = ((const float4*)src)[1];
                alignas(16) unsigned short o[8];
                o[0] = f2bf(v0.x); o[1] = f2bf(v0.y);
                o[2] = f2bf(v0.z); o[3] = f2bf(v0.w);
                o[4] = f2bf(v1.x); o[5] = f2bf(v1.y);
                o[6] = f2bf(v1.z); o[7] = f2bf(v1.w);
                if (p == 0) sv0 = *(short8*)o; else sv1 = *(short8*)o;
            }
        }
    };
    auto stage_write = [&](int buf) {
        *(short8*)(Blds[buf] + tid * 16)         = sv0;
        *(short8*)(Blds[buf] + 16384 + tid * 16) = sv1;
    };

    // prologue
    stage_issue(0);
    stage_write(0);
    float4 xa = *(const float4*)(xp);
    __syncthreads();

#pragma unroll 1
    for (int s = 0; s < NSTEP; ++s) {
        const int buf = s & 1;

        if (s + 1 < NSTEP) stage_issue(s + 1);
        float4 xn = xa;
        if (s + 1 < NSTEP) xn = *(const float4*)(xp + (size_t)(s + 1) * 4);

#pragma unroll
        for (int t = 0; t < 4; ++t) {
            // Chebyshev chain for i = s*4+t: lane half selects cos/sin
            const float xv = xa[t];
            const float s1f = __sinf(xv);
            const float c1f = __cosf(xv);
            float p1 = lhalf ? s1f : c1f;
            float p2 = p2init;
            alignas(16) __hip_bfloat16 h[8];
            h[0] = __float2bfloat16(p1);
            const float tc = c1f + c1f;
#pragma unroll
            for (int k = 1; k < 8; ++k) {
                const float pn = tc * p1 - p2;
                p2 = p1; p1 = pn;
                h[k] = __float2bfloat16(pn);
            }
            const short8 af = *(const short8*)h;

            const short8 b0 = *(const short8*)(
                Blds[buf] + (t * 8 + cg0) * 1024 + l * 16);
            const short8 b1 = *(const short8*)(
                Blds[buf] + (t * 8 + cg0 + 1) * 1024 + l * 16);

            __builtin_amdgcn_s_setprio(1);
            acc[0] = __builtin_amdgcn_mfma_f32_32x32x16_bf16(
                af, b0, acc[0], 0, 0, 0);
            acc[1] = __builtin_amdgcn_mfma_f32_32x32x16_bf16(
                af, b1, acc[1], 0, 0, 0);
            __builtin_amdgcn_s_setprio(0);
        }

        if (s + 1 < NSTEP) stage_write(buf ^ 1);
        __syncthreads();
        xa = xn;
    }

    // epilogue: 32x32 C/D: col = lane&31, row = (r&3) + 8*(r>>2) + 4*lhalf
#pragma unroll
    for (int n = 0; n < 2; ++n)
#pragma unroll
        for (int r = 0; r < 16; ++r) {
            const int orow = bm0 + wm * 32 + (r & 3) + 8 * (r >> 2) + 4 * lhalf;
            const int ocol = wn * 64 + n * 32 + lrow;
            out[(size_t)orow * 256 + ocol] = acc[n][r];
        }
}

extern "C" void kernel_launch(void* const* d_in, const int* in_sizes, int n_in,
                              void* d_out, int out_size, void* d_ws, size_t ws_size,
                              hipStream_t stream) {
    const float* x  = (const float*)d_in[0];
    const float* ca = (const float*)d_in[1];
    const float* cb = (const float*)d_in[2];
    float* out = (float*)d_out;

    const size_t wt_bytes = (size_t)131072 * 16;   // 2 MiB

    if (ws_size >= wt_bytes) {
        unsigned short* wt = (unsigned short*)d_ws;
        pack_w_kernel<<<512, 256, 0, stream>>>(ca, cb, wt);
        kan_gemm<true><<<256, 1024, 0, stream>>>(x, wt, ca, cb, out);
    } else {
        kan_gemm<false><<<256, 1024, 0, stream>>>(x, nullptr, ca, cb, out);
    }
}